// Round 12
// baseline (1786.472 us; speedup 1.0000x reference)
//
#include <hip/hip_runtime.h>

#define NE 8
#define NTOK 8192
#define NDIM 1024
#define NFF 4096

typedef short bf16x8 __attribute__((ext_vector_type(8)));
typedef float f32x4 __attribute__((ext_vector_type(4)));
typedef unsigned short us_t;
typedef us_t us4 __attribute__((ext_vector_type(4)));
typedef us_t us8 __attribute__((ext_vector_type(8)));

#define MFMA16 __builtin_amdgcn_mfma_f32_16x16x32_bf16

__device__ __forceinline__ us_t f2bf(float f) {
  unsigned int u = __float_as_uint(f);
  u += 0x7fffu + ((u >> 16) & 1u);
  return (us_t)(u >> 16);
}

__device__ __forceinline__ void gload16(const void* g, void* l) {
  __builtin_amdgcn_global_load_lds(
      (const __attribute__((address_space(1))) void*)g,
      (__attribute__((address_space(3))) void*)l, 16, 0, 0);
}

// ---------------- router: fp32 logits, top-2, gates, expert lists, x->bf16 ----------------
__global__ __launch_bounds__(256) void router_kernel(
    const float* __restrict__ x, const float* __restrict__ wr,
    int* __restrict__ counts, int* __restrict__ tok_list,
    int4* __restrict__ tok4, float2* __restrict__ gate2,
    us_t* __restrict__ xbf)
{
  __shared__ float wr_s[NE * NDIM];
  int tid = threadIdx.x;
#pragma unroll
  for (int i = 0; i < 8; ++i)
    ((float4*)wr_s)[tid + 256 * i] = ((const float4*)wr)[tid + 256 * i];
  __syncthreads();
  int w = tid >> 6, l = tid & 63;
  int t = blockIdx.x * 4 + w;
  float4 xv[4];
#pragma unroll
  for (int j = 0; j < 4; ++j) xv[j] = ((const float4*)x)[(size_t)t * 256 + j * 64 + l];
#pragma unroll
  for (int j = 0; j < 4; ++j) {
    us4 o;
    o.x = f2bf(xv[j].x); o.y = f2bf(xv[j].y); o.z = f2bf(xv[j].z); o.w = f2bf(xv[j].w);
    ((us4*)xbf)[(size_t)t * 256 + j * 64 + l] = o;
  }
  float logits[NE];
#pragma unroll
  for (int e = 0; e < NE; ++e) {
    float p = 0.f;
#pragma unroll
    for (int j = 0; j < 4; ++j) {
      float4 wv = ((const float4*)wr_s)[e * 256 + j * 64 + l];
      p += xv[j].x * wv.x + xv[j].y * wv.y + xv[j].z * wv.z + xv[j].w * wv.w;
    }
#pragma unroll
    for (int s = 32; s > 0; s >>= 1) p += __shfl_xor(p, s, 64);
    logits[e] = p;
  }
  if (l == 0) {
    int e1 = 0; float v1 = logits[0];
#pragma unroll
    for (int e = 1; e < NE; ++e) if (logits[e] > v1) { v1 = logits[e]; e1 = e; }
    int e2 = -1; float v2 = -3.4e38f;
#pragma unroll
    for (int e = 0; e < NE; ++e) if (e != e1 && logits[e] > v2) { v2 = logits[e]; e2 = e; }
    float ge = expf(v2 - v1);
    float g1 = 1.f / (1.f + ge);
    float g2 = 1.f - g1;
    int i1 = atomicAdd(&counts[e1], 1);
    tok_list[e1 * NTOK + i1] = t;
    int i2 = atomicAdd(&counts[e2], 1);
    tok_list[e2 * NTOK + i2] = t;
    tok4[t] = make_int4(e1, i1, e2, i2);
    gate2[t] = make_float2(g1, g2);
  }
}

__global__ void prefix8(const int* __restrict__ counts, int* __restrict__ offsets) {
  if (threadIdx.x == 0) {
    int s = 0;
    for (int e = 0; e < NE; ++e) { offsets[e] = s; s += counts[e]; }
  }
}

// ---------------- transpose + fp32->bf16: in [R][C] fp32 -> out [C][R] bf16, per expert z ----------------
// 16B (us8) stores
__global__ __launch_bounds__(256) void transpose_cvt(
    const float* __restrict__ in, us_t* __restrict__ out, int R, int C)
{
  __shared__ float tile[64][65];
  int e = blockIdx.z;
  const float* ip = in + (size_t)e * R * C;
  us_t* op = out + (size_t)e * R * C;
  int r0 = blockIdx.y * 64, c0 = blockIdx.x * 64;
  int tid = threadIdx.x;
#pragma unroll
  for (int q = 0; q < 4; ++q) {
    int id = tid + 256 * q;
    int rr = id >> 4, c4 = id & 15;
    float4 v = *(const float4*)&ip[(size_t)(r0 + rr) * C + c0 + c4 * 4];
    tile[rr][c4 * 4 + 0] = v.x; tile[rr][c4 * 4 + 1] = v.y;
    tile[rr][c4 * 4 + 2] = v.z; tile[rr][c4 * 4 + 3] = v.w;
  }
  __syncthreads();
#pragma unroll
  for (int q = 0; q < 2; ++q) {
    int id = tid + 256 * q;          // [0,512)
    int cc = id >> 3, r8 = id & 7;   // 64 cols x 8 row-groups
    us8 o;
#pragma unroll
    for (int j = 0; j < 8; ++j) o[j] = f2bf(tile[r8 * 8 + j][cc]);
    *(us8*)&op[(size_t)(c0 + cc) * R + r0 + r8 * 8] = o;
  }
}

// ---------------- GEMM1: h = silu(x@w1_a + b1_a) * (x@w1_b + b1_b), gathered rows ----------------
// r1-form body (measured 403us). Flat grid 16384, slab XCD swizzle (assumes xcd = blockIdx%8):
// XCD c owns mt in [8c, 8c+8): A-set 2MB L2-resident; 8 consecutive same-XCD blocks share one B-panel.
__global__ __launch_bounds__(256) void gemm1_swiglu(
    const us_t* __restrict__ xbf,   // [NTOK][NDIM] bf16
    const us_t* __restrict__ w1T,   // [NE][2FF][NDIM] bf16 (n-major, k contiguous)
    const float* __restrict__ b1,   // [NE][2FF]
    const int* __restrict__ counts, const int* __restrict__ offsets,
    const int* __restrict__ tok_list,
    us_t* __restrict__ hbuf)        // [16384][NFF] bf16
{
  const int b = blockIdx.x;
  const int xcd = b & 7, k = b >> 3;          // k in [0,2048)
  const int mt = xcd * 8 + (k & 7);           // [0,64)
  const int ct = (k >> 3) & 31;               // [0,32)
  const int e  = k >> 8;                      // [0,8)

  const int cnt = counts[e];
  if (mt * 128 >= cnt) return;
  const int off = offsets[e];
  const int tid = threadIdx.x, w = tid >> 6, l = tid & 63;
  const int wr_ = w >> 1, wc = w & 1;

  __shared__ char ldsA[16384];   // [128 rows][64 k] bf16, 128B rows, xor-swizzled
  __shared__ char ldsB[32768];   // [256 cols][64 k] bf16 (0-127 a-half, 128-255 b-half)
  __shared__ int tok_l[128];

  if (tid < 128) {
    int r = mt * 128 + tid;
    tok_l[tid] = tok_list[e * NTOK + (r < cnt ? r : cnt - 1)];
  }
  __syncthreads();

  f32x4 zf = {0.f, 0.f, 0.f, 0.f};
  f32x4 acc[2][4][4];
#pragma unroll
  for (int h_ = 0; h_ < 2; ++h_)
#pragma unroll
    for (int cg = 0; cg < 4; ++cg)
#pragma unroll
      for (int rg = 0; rg < 4; ++rg) acc[h_][cg][rg] = zf;

  const size_t w1base = (size_t)e * 2 * NFF * NDIM;

  for (int kt = 0; kt < NDIM; kt += 64) {
    __syncthreads();
#pragma unroll
    for (int i = 0; i < 12; ++i) {
      int c = w + i * 4;               // chunk id, 48 x 1KB
      const us_t* gsrc; char* ldst;
      if (c < 16) {                    // A tile, 16KB
        int p = c * 1024 + l * 16;
        int row = p >> 7;
        int ir = (p & 127) ^ ((row & 7) << 4);
        gsrc = xbf + (size_t)tok_l[row] * NDIM + kt + (ir >> 1);
        ldst = ldsA + c * 1024;
      } else {                         // B tile, 32KB
        int cb = c - 16;
        int p = cb * 1024 + l * 16;
        int row = p >> 7;              // 0..255
        int ir = (p & 127) ^ ((row & 7) << 4);
        int ncol = (row < 128) ? (ct * 128 + row) : (NFF + ct * 128 + row - 128);
        gsrc = w1T + w1base + (size_t)ncol * NDIM + kt + (ir >> 1);
        ldst = ldsB + cb * 1024;
      }
      gload16(gsrc, ldst);
    }
    __syncthreads();
#pragma unroll
    for (int ks = 0; ks < 2; ++ks) {
      bf16x8 af[4];
#pragma unroll
      for (int rg = 0; rg < 4; ++rg) {
        int row = wr_ * 64 + rg * 16 + (l & 15);
        int ir = (ks * 64 + (l >> 4) * 16) ^ ((row & 7) << 4);
        af[rg] = *(const bf16x8*)(ldsA + row * 128 + ir);
      }
#pragma unroll
      for (int h_ = 0; h_ < 2; ++h_)
#pragma unroll
        for (int cg = 0; cg < 4; ++cg) {
          int crow = h_ * 128 + wc * 64 + cg * 16 + (l & 15);
          int ir = (ks * 64 + (l >> 4) * 16) ^ ((crow & 7) << 4);
          bf16x8 bfr = *(const bf16x8*)(ldsB + crow * 128 + ir);
#pragma unroll
          for (int rg = 0; rg < 4; ++rg)
            acc[h_][cg][rg] = MFMA16(af[rg], bfr, acc[h_][cg][rg], 0, 0, 0);
        }
    }
  }

  // epilogue: u_a + b1a, u_b + b1b, h = silu(a)*b -> bf16
  float b1a[4], b1b[4];
#pragma unroll
  for (int cg = 0; cg < 4; ++cg) {
    int n_a = ct * 128 + wc * 64 + cg * 16 + (l & 15);
    b1a[cg] = b1[e * 2 * NFF + n_a];
    b1b[cg] = b1[e * 2 * NFF + NFF + n_a];
  }
#pragma unroll
  for (int cg = 0; cg < 4; ++cg) {
    int n_a = ct * 128 + wc * 64 + cg * 16 + (l & 15);
#pragma unroll
    for (int rg = 0; rg < 4; ++rg) {
#pragma unroll
      for (int j = 0; j < 4; ++j) {
        int rt = wr_ * 64 + rg * 16 + (l >> 4) * 4 + j;
        int r = mt * 128 + rt;
        if (r < cnt) {
          float a = acc[0][cg][rg][j] + b1a[cg];
          float b = acc[1][cg][rg][j] + b1b[cg];
          float hv = (a / (1.f + __expf(-a))) * b;
          hbuf[(size_t)(off + r) * NFF + n_a] = f2bf(hv);
        }
      }
    }
  }
}

// ---------------- GEMM2: y = h@w2 + b2 -> ybuf[slot] (no atomics) ----------------
// r4-form body (hoisted offsets, 128x128). Flat grid 4096, swizzle: each (nt,e) B-panel
// owned by one XCD; 64 consecutive same-XCD blocks share it (1MB L2-hot).
__global__ __launch_bounds__(256) void gemm2_slot(
    const us_t* __restrict__ hbuf,  // [16384][NFF] bf16
    const us_t* __restrict__ w2T,   // [NE][NDIM][NFF] bf16
    const float* __restrict__ b2,   // [NE][NDIM]
    const int* __restrict__ counts, const int* __restrict__ offsets,
    float* __restrict__ ybuf)       // [16384][NDIM] f32
{
  const int b = blockIdx.x;
  const int xcd = b & 7, k = b >> 3;     // k in [0,512)
  const int mt = k & 63;                 // fastest: 64 same-XCD blocks share B-panel
  const int combo = xcd + 8 * (k >> 6);  // [0,64)
  const int nt = combo & 7, e = combo >> 3;

  const int cnt = counts[e];
  if (mt * 128 >= cnt) return;
  const int off = offsets[e];
  const int tid = threadIdx.x, w = tid >> 6, l = tid & 63;
  const int wr_ = w >> 1, wc = w & 1;

  __shared__ char ldsA[16384];
  __shared__ char ldsB[16384];

  // hoisted staging offsets (bytes): chunk c = w + i*4; i<4 -> A (hbuf), else B (w2T)
  unsigned int soff[8];
#pragma unroll
  for (int i = 0; i < 8; ++i) {
    int c = w + i * 4;
    if (i < 4) {
      int p = c * 1024 + l * 16;
      int row = p >> 7;
      int ir = (p & 127) ^ ((row & 7) << 4);
      int r = mt * 128 + row; if (r >= cnt) r = cnt - 1;
      soff[i] = (unsigned int)((off + r) * (NFF * 2) + ir);
    } else {
      int cb = c - 16;
      int p = cb * 1024 + l * 16;
      int row = p >> 7;
      int ir = (p & 127) ^ ((row & 7) << 4);
      soff[i] = (unsigned int)((nt * 128 + row) * (NFF * 2) + ir);
    }
  }

  f32x4 zf = {0.f, 0.f, 0.f, 0.f};
  f32x4 acc[4][4];
#pragma unroll
  for (int cg = 0; cg < 4; ++cg)
#pragma unroll
    for (int rg = 0; rg < 4; ++rg) acc[cg][rg] = zf;

  const char* hB = (const char*)hbuf;
  const char* wB = (const char*)w2T + (size_t)e * NDIM * NFF * 2;

  for (int ktb = 0; ktb < NFF * 2; ktb += 128) {
    __syncthreads();
#pragma unroll
    for (int i = 0; i < 4; ++i)
      gload16(hB + soff[i] + ktb, ldsA + (w + i * 4) * 1024);
#pragma unroll
    for (int i = 4; i < 8; ++i)
      gload16(wB + soff[i] + ktb, ldsB + (w + i * 4 - 16) * 1024);
    __syncthreads();
#pragma unroll
    for (int ks = 0; ks < 2; ++ks) {
      bf16x8 af[4];
#pragma unroll
      for (int rg = 0; rg < 4; ++rg) {
        int row = wr_ * 64 + rg * 16 + (l & 15);
        int ir = (ks * 64 + (l >> 4) * 16) ^ ((row & 7) << 4);
        af[rg] = *(const bf16x8*)(ldsA + row * 128 + ir);
      }
#pragma unroll
      for (int cg = 0; cg < 4; ++cg) {
        int crow = wc * 64 + cg * 16 + (l & 15);
        int ir = (ks * 64 + (l >> 4) * 16) ^ ((crow & 7) << 4);
        bf16x8 bfr = *(const bf16x8*)(ldsB + crow * 128 + ir);
#pragma unroll
        for (int rg = 0; rg < 4; ++rg)
          acc[cg][rg] = MFMA16(af[rg], bfr, acc[cg][rg], 0, 0, 0);
      }
    }
  }

#pragma unroll
  for (int cg = 0; cg < 4; ++cg) {
    int col = nt * 128 + wc * 64 + cg * 16 + (l & 15);
    float b2v = b2[e * NDIM + col];
#pragma unroll
    for (int rg = 0; rg < 4; ++rg) {
#pragma unroll
      for (int j = 0; j < 4; ++j) {
        int rt = wr_ * 64 + rg * 16 + (l >> 4) * 4 + j;
        int r = mt * 128 + rt;
        if (r < cnt)
          ybuf[(size_t)(off + r) * NDIM + col] = acc[cg][rg][j] + b2v;
      }
    }
  }
}

// ---------------- combine: out[t] = g1*y[slot1] + g2*y[slot2] ----------------
__global__ __launch_bounds__(256) void combine_kernel(
    const float* __restrict__ ybuf, const int* __restrict__ offsets,
    const int4* __restrict__ tok4, const float2* __restrict__ gate2,
    float* __restrict__ out)
{
  int t = blockIdx.x;
  int4 p = tok4[t];
  float2 g = gate2[t];
  int s1 = offsets[p.x] + p.y;
  int s2 = offsets[p.z] + p.w;
  const float4* y1 = (const float4*)(ybuf + (size_t)s1 * NDIM);
  const float4* y2 = (const float4*)(ybuf + (size_t)s2 * NDIM);
  float4 a = y1[threadIdx.x];
  float4 b = y2[threadIdx.x];
  float4 o;
  o.x = g.x * a.x + g.y * b.x;
  o.y = g.x * a.y + g.y * b.y;
  o.z = g.x * a.z + g.y * b.z;
  o.w = g.x * a.w + g.y * b.w;
  ((float4*)(out + (size_t)t * NDIM))[threadIdx.x] = o;
}

extern "C" void kernel_launch(void* const* d_in, const int* in_sizes, int n_in,
                              void* d_out, int out_size, void* d_ws, size_t ws_size,
                              hipStream_t stream) {
  const float* x  = (const float*)d_in[0];
  const float* wr = (const float*)d_in[1];
  const float* w1 = (const float*)d_in[2];
  const float* b1 = (const float*)d_in[3];
  const float* w2 = (const float*)d_in[4];
  const float* b2 = (const float*)d_in[5];
  float* out = (float*)d_out;
  char* ws = (char*)d_ws;

  // workspace layout (~286 MB)
  int*    counts   = (int*)(ws + 0);                          // 256 B
  int*    offsets  = (int*)(ws + 256);                        // 256 B
  int*    tok_list = (int*)(ws + 512);                        // 256 KB
  int4*   tok4     = (int4*)(ws + 512 + 262144);              // 128 KB
  float2* gate2    = (float2*)(ws + 512 + 262144 + 131072);   // 64 KB
  us_t*   xbf      = (us_t*)(ws + 524800);                    // 16 MB
  us_t*   hbuf     = (us_t*)(ws + 524800 + (size_t)NTOK * NDIM * 2);            // 134 MB
  us_t*   wT       = (us_t*)(ws + 524800 + (size_t)NTOK * NDIM * 2
                                          + (size_t)2 * NTOK * NFF * 2);        // 128 MB region
  float*  ybuf     = (float*)((char*)wT + 67108864);          // 64 MB (upper half of wT region)

  hipMemsetAsync(counts, 0, 32, stream);

  router_kernel<<<NTOK / 4, 256, 0, stream>>>(x, wr, counts, tok_list, tok4, gate2, xbf);
  prefix8<<<1, 64, 0, stream>>>(counts, offsets);

  // w1 [E][1024][8192] -> w1T bf16 [E][8192][1024]
  transpose_cvt<<<dim3(2 * NFF / 64, NDIM / 64, NE), 256, 0, stream>>>(w1, wT, NDIM, 2 * NFF);
  gemm1_swiglu<<<16384, 256, 0, stream>>>(
      xbf, wT, b1, counts, offsets, tok_list, hbuf);

  // w2 [E][4096][1024] -> w2T bf16 [E][1024][4096]  (reuses lower half of wT)
  transpose_cvt<<<dim3(NDIM / 64, NFF / 64, NE), 256, 0, stream>>>(w2, wT, NFF, NDIM);
  gemm2_slot<<<4096, 256, 0, stream>>>(
      hbuf, wT, b2, counts, offsets, ybuf);

  combine_kernel<<<NTOK, 256, 0, stream>>>(ybuf, offsets, tok4, gate2, out);
}

// Round 13
// 957.348 us; speedup vs baseline: 1.8661x; 1.8661x over previous
//
#include <hip/hip_runtime.h>

#define NE 8
#define NTOK 8192
#define NDIM 1024
#define NFF 4096

typedef short bf16x8 __attribute__((ext_vector_type(8)));
typedef float f32x4 __attribute__((ext_vector_type(4)));
typedef unsigned short us_t;
typedef us_t us4 __attribute__((ext_vector_type(4)));
typedef us_t us8 __attribute__((ext_vector_type(8)));

#define MFMA16 __builtin_amdgcn_mfma_f32_16x16x32_bf16

__device__ __forceinline__ us_t f2bf(float f) {
  unsigned int u = __float_as_uint(f);
  u += 0x7fffu + ((u >> 16) & 1u);
  return (us_t)(u >> 16);
}

__device__ __forceinline__ void gload16(const void* g, void* l) {
  __builtin_amdgcn_global_load_lds(
      (const __attribute__((address_space(1))) void*)g,
      (__attribute__((address_space(3))) void*)l, 16, 0, 0);
}

// ---------------- router: fp32 logits, top-2, gates, expert lists, x->bf16 ----------------
__global__ __launch_bounds__(256) void router_kernel(
    const float* __restrict__ x, const float* __restrict__ wr,
    int* __restrict__ counts, int* __restrict__ tok_list,
    int4* __restrict__ tok4, float2* __restrict__ gate2,
    us_t* __restrict__ xbf)
{
  __shared__ float wr_s[NE * NDIM];
  int tid = threadIdx.x;
#pragma unroll
  for (int i = 0; i < 8; ++i)
    ((float4*)wr_s)[tid + 256 * i] = ((const float4*)wr)[tid + 256 * i];
  __syncthreads();
  int w = tid >> 6, l = tid & 63;
  int t = blockIdx.x * 4 + w;
  float4 xv[4];
#pragma unroll
  for (int j = 0; j < 4; ++j) xv[j] = ((const float4*)x)[(size_t)t * 256 + j * 64 + l];
#pragma unroll
  for (int j = 0; j < 4; ++j) {
    us4 o;
    o.x = f2bf(xv[j].x); o.y = f2bf(xv[j].y); o.z = f2bf(xv[j].z); o.w = f2bf(xv[j].w);
    ((us4*)xbf)[(size_t)t * 256 + j * 64 + l] = o;
  }
  float logits[NE];
#pragma unroll
  for (int e = 0; e < NE; ++e) {
    float p = 0.f;
#pragma unroll
    for (int j = 0; j < 4; ++j) {
      float4 wv = ((const float4*)wr_s)[e * 256 + j * 64 + l];
      p += xv[j].x * wv.x + xv[j].y * wv.y + xv[j].z * wv.z + xv[j].w * wv.w;
    }
#pragma unroll
    for (int s = 32; s > 0; s >>= 1) p += __shfl_xor(p, s, 64);
    logits[e] = p;
  }
  if (l == 0) {
    int e1 = 0; float v1 = logits[0];
#pragma unroll
    for (int e = 1; e < NE; ++e) if (logits[e] > v1) { v1 = logits[e]; e1 = e; }
    int e2 = -1; float v2 = -3.4e38f;
#pragma unroll
    for (int e = 0; e < NE; ++e) if (e != e1 && logits[e] > v2) { v2 = logits[e]; e2 = e; }
    float ge = expf(v2 - v1);
    float g1 = 1.f / (1.f + ge);
    float g2 = 1.f - g1;
    int i1 = atomicAdd(&counts[e1], 1);
    tok_list[e1 * NTOK + i1] = t;
    int i2 = atomicAdd(&counts[e2], 1);
    tok_list[e2 * NTOK + i2] = t;
    tok4[t] = make_int4(e1, i1, e2, i2);
    gate2[t] = make_float2(g1, g2);
  }
}

__global__ void prefix8(const int* __restrict__ counts, int* __restrict__ offsets) {
  if (threadIdx.x == 0) {
    int s = 0;
    for (int e = 0; e < NE; ++e) { offsets[e] = s; s += counts[e]; }
  }
}

// ---------------- transpose + fp32->bf16: in [R][C] fp32 -> out [C][R] bf16, per expert z ----------------
// 16B (us8) stores
__global__ __launch_bounds__(256) void transpose_cvt(
    const float* __restrict__ in, us_t* __restrict__ out, int R, int C)
{
  __shared__ float tile[64][65];
  int e = blockIdx.z;
  const float* ip = in + (size_t)e * R * C;
  us_t* op = out + (size_t)e * R * C;
  int r0 = blockIdx.y * 64, c0 = blockIdx.x * 64;
  int tid = threadIdx.x;
#pragma unroll
  for (int q = 0; q < 4; ++q) {
    int id = tid + 256 * q;
    int rr = id >> 4, c4 = id & 15;
    float4 v = *(const float4*)&ip[(size_t)(r0 + rr) * C + c0 + c4 * 4];
    tile[rr][c4 * 4 + 0] = v.x; tile[rr][c4 * 4 + 1] = v.y;
    tile[rr][c4 * 4 + 2] = v.z; tile[rr][c4 * 4 + 3] = v.w;
  }
  __syncthreads();
#pragma unroll
  for (int q = 0; q < 2; ++q) {
    int id = tid + 256 * q;          // [0,512)
    int cc = id >> 3, r8 = id & 7;   // 64 cols x 8 row-groups
    us8 o;
#pragma unroll
    for (int j = 0; j < 8; ++j) o[j] = f2bf(tile[r8 * 8 + j][cc]);
    *(us8*)&op[(size_t)(c0 + cc) * R + r0 + r8 * 8] = o;
  }
}

// ---------------- GEMM1: h = silu(x@w1_a + b1_a) * (x@w1_b + b1_b), gathered rows ----------------
// round-1 measured-403us form, plain 3-D grid dim3(32,64,8).
// NOTE: with b = ct + 32*mt + 2048*e and xcd = b%8, all 16 active readers of a
// w1T B-panel (same ct,e) land on xcd = ct%8 — B-panel L2 locality is already ideal.
// Do NOT remap blockIdx here (round-8/12 regressions).
__global__ __launch_bounds__(256) void gemm1_swiglu(
    const us_t* __restrict__ xbf,   // [NTOK][NDIM] bf16
    const us_t* __restrict__ w1T,   // [NE][2FF][NDIM] bf16 (n-major, k contiguous)
    const float* __restrict__ b1,   // [NE][2FF]
    const int* __restrict__ counts, const int* __restrict__ offsets,
    const int* __restrict__ tok_list,
    us_t* __restrict__ hbuf)        // [16384][NFF] bf16
{
  const int e = blockIdx.z, mt = blockIdx.y, ct = blockIdx.x;
  const int cnt = counts[e];
  if (mt * 128 >= cnt) return;
  const int off = offsets[e];
  const int tid = threadIdx.x, w = tid >> 6, l = tid & 63;
  const int wr_ = w >> 1, wc = w & 1;

  __shared__ char ldsA[16384];   // [128 rows][64 k] bf16, 128B rows, xor-swizzled
  __shared__ char ldsB[32768];   // [256 cols][64 k] bf16 (0-127 a-half, 128-255 b-half)
  __shared__ int tok_l[128];

  if (tid < 128) {
    int r = mt * 128 + tid;
    tok_l[tid] = tok_list[e * NTOK + (r < cnt ? r : cnt - 1)];
  }
  __syncthreads();

  f32x4 zf = {0.f, 0.f, 0.f, 0.f};
  f32x4 acc[2][4][4];
#pragma unroll
  for (int h_ = 0; h_ < 2; ++h_)
#pragma unroll
    for (int cg = 0; cg < 4; ++cg)
#pragma unroll
      for (int rg = 0; rg < 4; ++rg) acc[h_][cg][rg] = zf;

  const size_t w1base = (size_t)e * 2 * NFF * NDIM;

  for (int kt = 0; kt < NDIM; kt += 64) {
    __syncthreads();
#pragma unroll
    for (int i = 0; i < 12; ++i) {
      int c = w + i * 4;               // chunk id, 48 x 1KB
      const us_t* gsrc; char* ldst;
      if (c < 16) {                    // A tile, 16KB
        int p = c * 1024 + l * 16;
        int row = p >> 7;
        int ir = (p & 127) ^ ((row & 7) << 4);
        gsrc = xbf + (size_t)tok_l[row] * NDIM + kt + (ir >> 1);
        ldst = ldsA + c * 1024;
      } else {                         // B tile, 32KB
        int cb = c - 16;
        int p = cb * 1024 + l * 16;
        int row = p >> 7;              // 0..255
        int ir = (p & 127) ^ ((row & 7) << 4);
        int ncol = (row < 128) ? (ct * 128 + row) : (NFF + ct * 128 + row - 128);
        gsrc = w1T + w1base + (size_t)ncol * NDIM + kt + (ir >> 1);
        ldst = ldsB + cb * 1024;
      }
      gload16(gsrc, ldst);
    }
    __syncthreads();
#pragma unroll
    for (int ks = 0; ks < 2; ++ks) {
      bf16x8 af[4];
#pragma unroll
      for (int rg = 0; rg < 4; ++rg) {
        int row = wr_ * 64 + rg * 16 + (l & 15);
        int ir = (ks * 64 + (l >> 4) * 16) ^ ((row & 7) << 4);
        af[rg] = *(const bf16x8*)(ldsA + row * 128 + ir);
      }
#pragma unroll
      for (int h_ = 0; h_ < 2; ++h_)
#pragma unroll
        for (int cg = 0; cg < 4; ++cg) {
          int crow = h_ * 128 + wc * 64 + cg * 16 + (l & 15);
          int ir = (ks * 64 + (l >> 4) * 16) ^ ((crow & 7) << 4);
          bf16x8 bfr = *(const bf16x8*)(ldsB + crow * 128 + ir);
#pragma unroll
          for (int rg = 0; rg < 4; ++rg)
            acc[h_][cg][rg] = MFMA16(af[rg], bfr, acc[h_][cg][rg], 0, 0, 0);
        }
    }
  }

  // epilogue: u_a + b1a, u_b + b1b, h = silu(a)*b -> bf16
  float b1a[4], b1b[4];
#pragma unroll
  for (int cg = 0; cg < 4; ++cg) {
    int n_a = ct * 128 + wc * 64 + cg * 16 + (l & 15);
    b1a[cg] = b1[e * 2 * NFF + n_a];
    b1b[cg] = b1[e * 2 * NFF + NFF + n_a];
  }
#pragma unroll
  for (int cg = 0; cg < 4; ++cg) {
    int n_a = ct * 128 + wc * 64 + cg * 16 + (l & 15);
#pragma unroll
    for (int rg = 0; rg < 4; ++rg) {
#pragma unroll
      for (int j = 0; j < 4; ++j) {
        int rt = wr_ * 64 + rg * 16 + (l >> 4) * 4 + j;
        int r = mt * 128 + rt;
        if (r < cnt) {
          float a = acc[0][cg][rg][j] + b1a[cg];
          float b = acc[1][cg][rg][j] + b1b[cg];
          float hv = (a / (1.f + __expf(-a))) * b;
          hbuf[(size_t)(off + r) * NFF + n_a] = f2bf(hv);
        }
      }
    }
  }
}

// ---------------- GEMM2: y = h@w2 + b2 -> ybuf[slot] (no atomics) ----------------
// round-12 form (inferred ~290us): hoisted offsets, 128x128, flat grid 4096 with
// work-balanced XCD swizzle — mt fastest within XCD, each (nt,e) B-panel XCD-owned.
__global__ __launch_bounds__(256) void gemm2_slot(
    const us_t* __restrict__ hbuf,  // [16384][NFF] bf16
    const us_t* __restrict__ w2T,   // [NE][NDIM][NFF] bf16
    const float* __restrict__ b2,   // [NE][NDIM]
    const int* __restrict__ counts, const int* __restrict__ offsets,
    float* __restrict__ ybuf)       // [16384][NDIM] f32
{
  const int b = blockIdx.x;
  const int xcd = b & 7, k = b >> 3;     // k in [0,512)
  const int mt = k & 63;                 // fastest: 64 same-XCD blocks share B-panel
  const int combo = xcd + 8 * (k >> 6);  // [0,64)
  const int nt = combo & 7, e = combo >> 3;

  const int cnt = counts[e];
  if (mt * 128 >= cnt) return;
  const int off = offsets[e];
  const int tid = threadIdx.x, w = tid >> 6, l = tid & 63;
  const int wr_ = w >> 1, wc = w & 1;

  __shared__ char ldsA[16384];
  __shared__ char ldsB[16384];

  // hoisted staging offsets (bytes): chunk c = w + i*4; i<4 -> A (hbuf), else B (w2T)
  unsigned int soff[8];
#pragma unroll
  for (int i = 0; i < 8; ++i) {
    int c = w + i * 4;
    if (i < 4) {
      int p = c * 1024 + l * 16;
      int row = p >> 7;
      int ir = (p & 127) ^ ((row & 7) << 4);
      int r = mt * 128 + row; if (r >= cnt) r = cnt - 1;
      soff[i] = (unsigned int)((off + r) * (NFF * 2) + ir);
    } else {
      int cb = c - 16;
      int p = cb * 1024 + l * 16;
      int row = p >> 7;
      int ir = (p & 127) ^ ((row & 7) << 4);
      soff[i] = (unsigned int)((nt * 128 + row) * (NFF * 2) + ir);
    }
  }

  f32x4 zf = {0.f, 0.f, 0.f, 0.f};
  f32x4 acc[4][4];
#pragma unroll
  for (int cg = 0; cg < 4; ++cg)
#pragma unroll
    for (int rg = 0; rg < 4; ++rg) acc[cg][rg] = zf;

  const char* hB = (const char*)hbuf;
  const char* wB = (const char*)w2T + (size_t)e * NDIM * NFF * 2;

  for (int ktb = 0; ktb < NFF * 2; ktb += 128) {
    __syncthreads();
#pragma unroll
    for (int i = 0; i < 4; ++i)
      gload16(hB + soff[i] + ktb, ldsA + (w + i * 4) * 1024);
#pragma unroll
    for (int i = 4; i < 8; ++i)
      gload16(wB + soff[i] + ktb, ldsB + (w + i * 4 - 16) * 1024);
    __syncthreads();
#pragma unroll
    for (int ks = 0; ks < 2; ++ks) {
      bf16x8 af[4];
#pragma unroll
      for (int rg = 0; rg < 4; ++rg) {
        int row = wr_ * 64 + rg * 16 + (l & 15);
        int ir = (ks * 64 + (l >> 4) * 16) ^ ((row & 7) << 4);
        af[rg] = *(const bf16x8*)(ldsA + row * 128 + ir);
      }
#pragma unroll
      for (int cg = 0; cg < 4; ++cg) {
        int crow = wc * 64 + cg * 16 + (l & 15);
        int ir = (ks * 64 + (l >> 4) * 16) ^ ((crow & 7) << 4);
        bf16x8 bfr = *(const bf16x8*)(ldsB + crow * 128 + ir);
#pragma unroll
        for (int rg = 0; rg < 4; ++rg)
          acc[cg][rg] = MFMA16(af[rg], bfr, acc[cg][rg], 0, 0, 0);
      }
    }
  }

#pragma unroll
  for (int cg = 0; cg < 4; ++cg) {
    int col = nt * 128 + wc * 64 + cg * 16 + (l & 15);
    float b2v = b2[e * NDIM + col];
#pragma unroll
    for (int rg = 0; rg < 4; ++rg) {
#pragma unroll
      for (int j = 0; j < 4; ++j) {
        int rt = wr_ * 64 + rg * 16 + (l >> 4) * 4 + j;
        int r = mt * 128 + rt;
        if (r < cnt)
          ybuf[(size_t)(off + r) * NDIM + col] = acc[cg][rg][j] + b2v;
      }
    }
  }
}

// ---------------- combine: out[t] = g1*y[slot1] + g2*y[slot2] ----------------
__global__ __launch_bounds__(256) void combine_kernel(
    const float* __restrict__ ybuf, const int* __restrict__ offsets,
    const int4* __restrict__ tok4, const float2* __restrict__ gate2,
    float* __restrict__ out)
{
  int t = blockIdx.x;
  int4 p = tok4[t];
  float2 g = gate2[t];
  int s1 = offsets[p.x] + p.y;
  int s2 = offsets[p.z] + p.w;
  const float4* y1 = (const float4*)(ybuf + (size_t)s1 * NDIM);
  const float4* y2 = (const float4*)(ybuf + (size_t)s2 * NDIM);
  float4 a = y1[threadIdx.x];
  float4 b = y2[threadIdx.x];
  float4 o;
  o.x = g.x * a.x + g.y * b.x;
  o.y = g.x * a.y + g.y * b.y;
  o.z = g.x * a.z + g.y * b.z;
  o.w = g.x * a.w + g.y * b.w;
  ((float4*)(out + (size_t)t * NDIM))[threadIdx.x] = o;
}

extern "C" void kernel_launch(void* const* d_in, const int* in_sizes, int n_in,
                              void* d_out, int out_size, void* d_ws, size_t ws_size,
                              hipStream_t stream) {
  const float* x  = (const float*)d_in[0];
  const float* wr = (const float*)d_in[1];
  const float* w1 = (const float*)d_in[2];
  const float* b1 = (const float*)d_in[3];
  const float* w2 = (const float*)d_in[4];
  const float* b2 = (const float*)d_in[5];
  float* out = (float*)d_out;
  char* ws = (char*)d_ws;

  // workspace layout (~286 MB)
  int*    counts   = (int*)(ws + 0);                          // 256 B
  int*    offsets  = (int*)(ws + 256);                        // 256 B
  int*    tok_list = (int*)(ws + 512);                        // 256 KB
  int4*   tok4     = (int4*)(ws + 512 + 262144);              // 128 KB
  float2* gate2    = (float2*)(ws + 512 + 262144 + 131072);   // 64 KB
  us_t*   xbf      = (us_t*)(ws + 524800);                    // 16 MB
  us_t*   hbuf     = (us_t*)(ws + 524800 + (size_t)NTOK * NDIM * 2);            // 134 MB
  us_t*   wT       = (us_t*)(ws + 524800 + (size_t)NTOK * NDIM * 2
                                          + (size_t)2 * NTOK * NFF * 2);        // 128 MB region
  float*  ybuf     = (float*)((char*)wT + 67108864);          // 64 MB (upper half of wT region)

  hipMemsetAsync(counts, 0, 32, stream);

  router_kernel<<<NTOK / 4, 256, 0, stream>>>(x, wr, counts, tok_list, tok4, gate2, xbf);
  prefix8<<<1, 64, 0, stream>>>(counts, offsets);

  // w1 [E][1024][8192] -> w1T bf16 [E][8192][1024]
  transpose_cvt<<<dim3(2 * NFF / 64, NDIM / 64, NE), 256, 0, stream>>>(w1, wT, NDIM, 2 * NFF);
  gemm1_swiglu<<<dim3(NFF / 128, NTOK / 128, NE), 256, 0, stream>>>(
      xbf, wT, b1, counts, offsets, tok_list, hbuf);

  // w2 [E][4096][1024] -> w2T bf16 [E][1024][4096]  (reuses lower half of wT)
  transpose_cvt<<<dim3(NDIM / 64, NFF / 64, NE), 256, 0, stream>>>(w2, wT, NFF, NDIM);
  gemm2_slot<<<4096, 256, 0, stream>>>(
      hbuf, wT, b2, counts, offsets, ybuf);

  combine_kernel<<<NTOK, 256, 0, stream>>>(ybuf, offsets, tok4, gate2, out);
}